// Round 1
// baseline (565.412 us; speedup 1.0000x reference)
//
#include <hip/hip_runtime.h>
#include <stdint.h>

// Problem constants (B=4, S=2048, K=4096, N=4096 -> M = B*S = 8192)
#define MDIM 8192
#define NDIM 4096
#define KDIM 4096

// GEMM tiling (m97 structure: 128x128 tile, BK=32, 4 waves, 16x16x32 bf16 MFMA)
#define BM 128
#define BN 128
#define BK 32

typedef __attribute__((ext_vector_type(8))) __bf16   bf16x8;
typedef __attribute__((ext_vector_type(4))) float    floatx4;
typedef __attribute__((ext_vector_type(8))) uint16_t ushort8x;

#define AS1 __attribute__((address_space(1)))
#define AS3 __attribute__((address_space(3)))

__device__ __forceinline__ uint16_t f2bf(float f) {
    // round-to-nearest-even fp32 -> bf16 (inputs are finite, no NaN handling needed)
    uint32_t u = __float_as_uint(f);
    u += 0x7FFFu + ((u >> 16) & 1u);
    return (uint16_t)(u >> 16);
}

// ---- fp32 -> bf16 conversion (x), 8 elems/thread, float4 loads ----
__global__ void cvt_x_kernel(const float* __restrict__ in, uint16_t* __restrict__ out, int n) {
    int i = (blockIdx.x * blockDim.x + threadIdx.x) * 8;
    if (i + 8 > n) return;
    const float4* p = (const float4*)(in + i);
    float4 a = p[0], b = p[1];
    ushort8x r;
    r[0] = f2bf(a.x); r[1] = f2bf(a.y); r[2] = f2bf(a.z); r[3] = f2bf(a.w);
    r[4] = f2bf(b.x); r[5] = f2bf(b.y); r[6] = f2bf(b.z); r[7] = f2bf(b.w);
    *(ushort8x*)(out + i) = r;
}

// ---- int32 (int8-valued) -> bf16 conversion (qw); exact: |q| <= 128 fits bf16 mantissa ----
__global__ void cvt_w_kernel(const int* __restrict__ in, uint16_t* __restrict__ out, int n) {
    int i = (blockIdx.x * blockDim.x + threadIdx.x) * 8;
    if (i + 8 > n) return;
    const int4* p = (const int4*)(in + i);
    int4 a = p[0], b = p[1];
    ushort8x r;
    r[0] = f2bf((float)a.x); r[1] = f2bf((float)a.y); r[2] = f2bf((float)a.z); r[3] = f2bf((float)a.w);
    r[4] = f2bf((float)b.x); r[5] = f2bf((float)b.y); r[6] = f2bf((float)b.z); r[7] = f2bf((float)b.w);
    *(ushort8x*)(out + i) = r;
}

// ---- bf16 GEMM, C[M,N] = A[M,K] * B[N,K]^T, epilogue: *sw + bias[n], fp32 out ----
// Block: 256 threads = 4 waves (2x2), each wave computes 64x64 via 4x4 grid of 16x16x32 MFMA.
// LDS tiles stored flat [128][32] (no padding -- required by global_load_lds contiguity).
__global__ __launch_bounds__(256) void gemm_bt_bf16(
        const uint16_t* __restrict__ A,   // [M,K] bf16 bits
        const uint16_t* __restrict__ Bm,  // [N,K] bf16 bits
        const float* __restrict__ sw,
        const float* __restrict__ bias,
        float* __restrict__ C)            // [M,N] fp32
{
    __shared__ uint16_t sA[BM * BK];  // 8 KB
    __shared__ uint16_t sB[BN * BK];  // 8 KB

    const int tid  = threadIdx.x;
    const int wave = tid >> 6;
    const int lane = tid & 63;
    const int wr   = wave >> 1;      // wave row (0..1) -> 64-row half of the tile
    const int wc   = wave & 1;       // wave col (0..1) -> 64-col half
    const int l16  = lane & 15;
    const int quad = lane >> 4;      // 0..3

    const int m0 = blockIdx.y * BM;
    const int n0 = blockIdx.x * BN;

    // Staging: flat element f of the [128][32] tile -> (row=f/32, col=f%32).
    // Per wave, per j in {0,1}: lanes cover f = wave*512 + j*2048 + lane*8
    // (LDS dest = wave-uniform base + lane*16B, matching global_load_lds HW semantics).
    const int fA = wave * 512 + lane * 8;
    const int rS = fA >> 5;
    const int cS = fA & 31;
    const uint16_t* gA0 = A  + (size_t)(m0 + rS) * KDIM + cS;
    const uint16_t* gA1 = gA0 + (size_t)64 * KDIM;        // j=1: f += 2048 -> row += 64
    const uint16_t* gB0 = Bm + (size_t)(n0 + rS) * KDIM + cS;
    const uint16_t* gB1 = gB0 + (size_t)64 * KDIM;
    uint16_t* lA0 = sA + wave * 512;          // wave-uniform LDS bases (elements)
    uint16_t* lA1 = lA0 + 2048;
    uint16_t* lB0 = sB + wave * 512;
    uint16_t* lB1 = lB0 + 2048;

    floatx4 acc[4][4];
#pragma unroll
    for (int i = 0; i < 4; i++)
#pragma unroll
        for (int j = 0; j < 4; j++) acc[i][j] = {0.f, 0.f, 0.f, 0.f};

    // LDS read bases for MFMA fragments:
    //   A-operand: A[m = lane&15][k = quad*8 + j]  -> row (wr*64 + mi*16 + l16), 8 contig k at quad*8
    //   B-operand: B^T[k][n]=B[n][k] -> row (wc*64 + ni*16 + l16), 8 contig k at quad*8
    const uint16_t* pA = sA + (wr * 64 + l16) * BK + quad * 8;
    const uint16_t* pB = sB + (wc * 64 + l16) * BK + quad * 8;

    for (int kt = 0; kt < KDIM; kt += BK) {
        __builtin_amdgcn_global_load_lds((AS1 const void*)(gA0 + kt), (AS3 void*)lA0, 16, 0, 0);
        __builtin_amdgcn_global_load_lds((AS1 const void*)(gA1 + kt), (AS3 void*)lA1, 16, 0, 0);
        __builtin_amdgcn_global_load_lds((AS1 const void*)(gB0 + kt), (AS3 void*)lB0, 16, 0, 0);
        __builtin_amdgcn_global_load_lds((AS1 const void*)(gB1 + kt), (AS3 void*)lB1, 16, 0, 0);
        __syncthreads();   // compiler emits vmcnt(0) drain before barrier

        bf16x8 afrag[4], bfrag[4];
#pragma unroll
        for (int i = 0; i < 4; i++) afrag[i] = *(const bf16x8*)(pA + i * 16 * BK);
#pragma unroll
        for (int i = 0; i < 4; i++) bfrag[i] = *(const bf16x8*)(pB + i * 16 * BK);

#pragma unroll
        for (int i = 0; i < 4; i++)
#pragma unroll
            for (int j = 0; j < 4; j++)
                acc[i][j] = __builtin_amdgcn_mfma_f32_16x16x32_bf16(
                    afrag[i], bfrag[j], acc[i][j], 0, 0, 0);

        __syncthreads();   // protect LDS before next stage (lgkmcnt drain covers ds_reads)
    }

    // Epilogue: C/D layout col = lane&15, row = quad*4 + reg  [measured m89/m91]
    const float scale = *sw;
#pragma unroll
    for (int i = 0; i < 4; i++) {
        const int row_base = m0 + wr * 64 + i * 16 + quad * 4;
#pragma unroll
        for (int j = 0; j < 4; j++) {
            const int col = n0 + wc * 64 + j * 16 + l16;
            const float b = bias[col];
#pragma unroll
            for (int r = 0; r < 4; r++) {
                C[(size_t)(row_base + r) * NDIM + col] = acc[i][j][r] * scale + b;
            }
        }
    }
}

// ---- correctness fallback if workspace is too small (not expected to run) ----
__global__ void gemm_naive_f32(const float* __restrict__ x, const int* __restrict__ qw,
                               const float* __restrict__ sw, const float* __restrict__ bias,
                               float* __restrict__ out) {
    size_t id = (size_t)blockIdx.x * blockDim.x + threadIdx.x;
    if (id >= (size_t)MDIM * NDIM) return;
    int m = (int)(id / NDIM);
    int n = (int)(id % NDIM);
    const float* xr = x + (size_t)m * KDIM;
    const int*   wr = qw + (size_t)n * KDIM;
    float acc = 0.f;
    for (int k = 0; k < KDIM; k++) acc += xr[k] * (float)wr[k];
    out[id] = acc * (*sw) + bias[n];
}

extern "C" void kernel_launch(void* const* d_in, const int* in_sizes, int n_in,
                              void* d_out, int out_size, void* d_ws, size_t ws_size,
                              hipStream_t stream) {
    const float* x    = (const float*)d_in[0];
    const int*   qw   = (const int*)d_in[1];
    const float* sw   = (const float*)d_in[2];
    const float* bias = (const float*)d_in[3];
    float* out = (float*)d_out;

    const size_t needA = (size_t)MDIM * KDIM * sizeof(uint16_t);  // 64 MiB
    const size_t needB = (size_t)NDIM * KDIM * sizeof(uint16_t);  // 32 MiB

    if (ws_size >= needA + needB) {
        uint16_t* Abf = (uint16_t*)d_ws;
        uint16_t* Bbf = (uint16_t*)((char*)d_ws + needA);

        const int nx = MDIM * KDIM;   // 33,554,432
        const int nw = NDIM * KDIM;   // 16,777,216
        cvt_x_kernel<<<nx / (256 * 8), 256, 0, stream>>>(x, Abf, nx);
        cvt_w_kernel<<<nw / (256 * 8), 256, 0, stream>>>(qw, Bbf, nw);

        dim3 grid(NDIM / BN, MDIM / BM);  // (32, 64) = 2048 blocks
        gemm_bt_bf16<<<grid, 256, 0, stream>>>(Abf, Bbf, sw, bias, out);
    } else {
        size_t total = (size_t)MDIM * NDIM;
        gemm_naive_f32<<<(total + 255) / 256, 256, 0, stream>>>(x, qw, sw, bias, out);
    }
}

// Round 2
// 561.471 us; speedup vs baseline: 1.0070x; 1.0070x over previous
//
#include <hip/hip_runtime.h>
#include <stdint.h>

// Problem constants (B=4, S=2048, K=4096, N=4096 -> M = B*S = 8192)
#define MDIM 8192
#define NDIM 4096
#define KDIM 4096

// GEMM tiling (m97 structure: 128x128 tile, BK=32, 4 waves, 16x16x32 bf16 MFMA)
#define BM 128
#define BN 128
#define BK 32

typedef __attribute__((ext_vector_type(8))) __bf16   bf16x8;
typedef __attribute__((ext_vector_type(4))) float    floatx4;
typedef __attribute__((ext_vector_type(8))) uint16_t ushort8x;

#define AS1 __attribute__((address_space(1)))
#define AS3 __attribute__((address_space(3)))

__device__ __forceinline__ uint16_t f2bf(float f) {
    // round-to-nearest-even fp32 -> bf16 (inputs finite). Ints |v|<=255 are exact.
    uint32_t u = __float_as_uint(f);
    u += 0x7FFFu + ((u >> 16) & 1u);
    return (uint16_t)(u >> 16);
}

// ---- fused conversion: x fp32->bf16 and qw int32->bf16, one dispatch ----
// Region [0, NX) handles x; [NX, NX+NW) handles qw. NX is a multiple of
// 8*256 so the x/qw boundary falls on a block boundary (no divergence).
__global__ void cvt_fused(const float* __restrict__ x, const int* __restrict__ qw,
                          uint16_t* __restrict__ Abf, uint16_t* __restrict__ Bbf) {
    const long NX = (long)MDIM * KDIM;
    long i = (long)(blockIdx.x * blockDim.x + threadIdx.x) * 8;
    ushort8x r;
    if (i < NX) {
        const float4* p = (const float4*)(x + i);
        float4 a = p[0], b = p[1];
        r[0] = f2bf(a.x); r[1] = f2bf(a.y); r[2] = f2bf(a.z); r[3] = f2bf(a.w);
        r[4] = f2bf(b.x); r[5] = f2bf(b.y); r[6] = f2bf(b.z); r[7] = f2bf(b.w);
        *(ushort8x*)(Abf + i) = r;
    } else {
        long j = i - NX;
        const int4* p = (const int4*)(qw + j);
        int4 a = p[0], b = p[1];
        r[0] = f2bf((float)a.x); r[1] = f2bf((float)a.y); r[2] = f2bf((float)a.z); r[3] = f2bf((float)a.w);
        r[4] = f2bf((float)b.x); r[5] = f2bf((float)b.y); r[6] = f2bf((float)b.z); r[7] = f2bf((float)b.w);
        *(ushort8x*)(Bbf + j) = r;
    }
}

// ---- bf16 GEMM, C[M,N] = A[M,K] * B[N,K]^T, epilogue: *sw + bias[n], fp32 out ----
// LDS tiles: logical [128 rows][4 chunks of 8 bf16 (16B)], stored with XOR swizzle
//   physical_chunk = logical_chunk ^ ((row>>1)&3)
// Staging stays lane-contiguous (global_load_lds requirement); the swizzle is
// realized by permuting each lane's GLOBAL source chunk within the same 64B row
// span (coalescing unchanged). Read side: 16-lane batches spread over all 8
// bank-quads at 2 lanes/quad -> 2-way aliasing, which is free (m136).
__global__ __launch_bounds__(256) void gemm_bt_bf16(
        const uint16_t* __restrict__ A,   // [M,K] bf16 bits
        const uint16_t* __restrict__ Bm,  // [N,K] bf16 bits
        const float* __restrict__ sw,
        const float* __restrict__ bias,
        float* __restrict__ C)            // [M,N] fp32
{
    __shared__ uint16_t sA[BM * BK];  // 8 KB
    __shared__ uint16_t sB[BN * BK];  // 8 KB

    const int tid  = threadIdx.x;
    const int wave = tid >> 6;
    const int lane = tid & 63;
    const int wr   = wave >> 1;      // wave row (0..1) -> 64-row half of tile
    const int wc   = wave & 1;       // wave col (0..1) -> 64-col half
    const int l16  = lane & 15;
    const int quad = lane >> 4;      // 0..3

    const int m0 = blockIdx.y * BM;
    const int n0 = blockIdx.x * BN;

    // ---- staging addresses ----
    // Physical flat element F = wave*512 + lane*8 -> physical row r = F>>5,
    // physical chunk p = lane&3. Source logical chunk c = p ^ ((r>>1)&3).
    const int rS = wave * 16 + (lane >> 2);          // physical row 0..63 (j=0)
    const int cS = ((lane & 3) ^ ((rS >> 1) & 3)) * 8;  // swizzled source k-offset
    const uint16_t* gA0 = A  + (size_t)(m0 + rS) * KDIM + cS;
    const uint16_t* gA1 = gA0 + (size_t)64 * KDIM;   // rows 64..127: (r+64>>1)&3 unchanged
    const uint16_t* gB0 = Bm + (size_t)(n0 + rS) * KDIM + cS;
    const uint16_t* gB1 = gB0 + (size_t)64 * KDIM;
    uint16_t* lA0 = sA + wave * 512;                 // wave-uniform LDS bases (elements)
    uint16_t* lA1 = lA0 + 2048;
    uint16_t* lB0 = sB + wave * 512;
    uint16_t* lB1 = lB0 + 2048;

    floatx4 acc[4][4];
#pragma unroll
    for (int i = 0; i < 4; i++)
#pragma unroll
        for (int j = 0; j < 4; j++) acc[i][j] = {0.f, 0.f, 0.f, 0.f};

    // ---- fragment read addresses ----
    // A-operand: A[m = l16 (+16i +64wr)][k = quad*8 + e]. Logical chunk = quad;
    // row R = wr*64 + i*16 + l16 -> (R>>1)&3 == (l16>>1)&3 (i*16, wr*64 are mult of 8/32).
    const int rdsw = ((quad ^ ((l16 >> 1) & 3)) * 8);
    const uint16_t* pA = sA + (wr * 64 + l16) * BK + rdsw;
    const uint16_t* pB = sB + (wc * 64 + l16) * BK + rdsw;

    for (int kt = 0; kt < KDIM; kt += BK) {
        __builtin_amdgcn_global_load_lds((AS1 const void*)(gA0 + kt), (AS3 void*)lA0, 16, 0, 0);
        __builtin_amdgcn_global_load_lds((AS1 const void*)(gA1 + kt), (AS3 void*)lA1, 16, 0, 0);
        __builtin_amdgcn_global_load_lds((AS1 const void*)(gB0 + kt), (AS3 void*)lB0, 16, 0, 0);
        __builtin_amdgcn_global_load_lds((AS1 const void*)(gB1 + kt), (AS3 void*)lB1, 16, 0, 0);
        __syncthreads();

        bf16x8 afrag[4], bfrag[4];
#pragma unroll
        for (int i = 0; i < 4; i++) afrag[i] = *(const bf16x8*)(pA + i * 16 * BK);
#pragma unroll
        for (int i = 0; i < 4; i++) bfrag[i] = *(const bf16x8*)(pB + i * 16 * BK);

#pragma unroll
        for (int i = 0; i < 4; i++)
#pragma unroll
            for (int j = 0; j < 4; j++)
                acc[i][j] = __builtin_amdgcn_mfma_f32_16x16x32_bf16(
                    afrag[i], bfrag[j], acc[i][j], 0, 0, 0);

        __syncthreads();
    }

    // Epilogue: C/D layout col = lane&15, row = quad*4 + reg  [measured m89/m91]
    const float scale = *sw;
#pragma unroll
    for (int i = 0; i < 4; i++) {
        const int row_base = m0 + wr * 64 + i * 16 + quad * 4;
#pragma unroll
        for (int j = 0; j < 4; j++) {
            const int col = n0 + wc * 64 + j * 16 + l16;
            const float b = bias[col];
#pragma unroll
            for (int r = 0; r < 4; r++) {
                C[(size_t)(row_base + r) * NDIM + col] = acc[i][j][r] * scale + b;
            }
        }
    }
}

// ---- correctness fallback if workspace is too small (not expected to run) ----
__global__ void gemm_naive_f32(const float* __restrict__ x, const int* __restrict__ qw,
                               const float* __restrict__ sw, const float* __restrict__ bias,
                               float* __restrict__ out) {
    size_t id = (size_t)blockIdx.x * blockDim.x + threadIdx.x;
    if (id >= (size_t)MDIM * NDIM) return;
    int m = (int)(id / NDIM);
    int n = (int)(id % NDIM);
    const float* xr = x + (size_t)m * KDIM;
    const int*   wr = qw + (size_t)n * KDIM;
    float acc = 0.f;
    for (int k = 0; k < KDIM; k++) acc += xr[k] * (float)wr[k];
    out[id] = acc * (*sw) + bias[n];
}

extern "C" void kernel_launch(void* const* d_in, const int* in_sizes, int n_in,
                              void* d_out, int out_size, void* d_ws, size_t ws_size,
                              hipStream_t stream) {
    const float* x    = (const float*)d_in[0];
    const int*   qw   = (const int*)d_in[1];
    const float* sw   = (const float*)d_in[2];
    const float* bias = (const float*)d_in[3];
    float* out = (float*)d_out;

    const size_t needA = (size_t)MDIM * KDIM * sizeof(uint16_t);  // 64 MiB
    const size_t needB = (size_t)NDIM * KDIM * sizeof(uint16_t);  // 32 MiB

    if (ws_size >= needA + needB) {
        uint16_t* Abf = (uint16_t*)d_ws;
        uint16_t* Bbf = (uint16_t*)((char*)d_ws + needA);

        const long nx = (long)MDIM * KDIM;   // 33,554,432 (multiple of 2048)
        const long nw = (long)NDIM * KDIM;   // 16,777,216
        const int cvt_blocks = (int)((nx + nw) / (256 * 8));  // 24576
        cvt_fused<<<cvt_blocks, 256, 0, stream>>>(x, qw, Abf, Bbf);

        dim3 grid(NDIM / BN, MDIM / BM);  // (32, 64) = 2048 blocks
        gemm_bt_bf16<<<grid, 256, 0, stream>>>(Abf, Bbf, sw, bias, out);
    } else {
        size_t total = (size_t)MDIM * NDIM;
        gemm_naive_f32<<<(total + 255) / 256, 256, 0, stream>>>(x, qw, sw, bias, out);
    }
}

// Round 3
// 434.132 us; speedup vs baseline: 1.3024x; 1.2933x over previous
//
#include <hip/hip_runtime.h>
#include <stdint.h>

// Problem constants (B=4, S=2048, K=4096, N=4096 -> M = B*S = 8192)
#define MDIM 8192
#define NDIM 4096
#define KDIM 4096

// GEMM tiling: 128x128 tile, BK=64 (i8 -> 64B rows), 4 waves (2x2),
// each wave 64x64 via 2x2 grid of mfma_i32_32x32x32_i8.
#define BM 128
#define BN 128
#define BK 64

typedef __attribute__((ext_vector_type(4)))  int i32x4;
typedef __attribute__((ext_vector_type(16))) int i32x16;

#define AS1 __attribute__((address_space(1)))
#define AS3 __attribute__((address_space(3)))

__device__ __forceinline__ int clamp127(int v) {
    return v > 127 ? 127 : (v < -127 ? -127 : v);
}

// ---- x fp32 -> int8, per-row symmetric quant (row = 4096 elems) ----
// One block per row. scales[row] = (amax/127) * sw  (dequant scale, sw folded in).
__global__ __launch_bounds__(256) void quant_x(
        const float* __restrict__ x, const float* __restrict__ sw,
        int8_t* __restrict__ Aq, float* __restrict__ scales) {
    const int row = blockIdx.x;
    const int t   = threadIdx.x;
    const float* xr = x + (size_t)row * KDIM;

    // thread t covers elems [t*16, t*16+16)
    const float4* px = (const float4*)(xr + t * 16);
    float4 v0 = px[0], v1 = px[1], v2 = px[2], v3 = px[3];

    float a = fabsf(v0.x);
    a = fmaxf(a, fabsf(v0.y)); a = fmaxf(a, fabsf(v0.z)); a = fmaxf(a, fabsf(v0.w));
    a = fmaxf(a, fabsf(v1.x)); a = fmaxf(a, fabsf(v1.y)); a = fmaxf(a, fabsf(v1.z)); a = fmaxf(a, fabsf(v1.w));
    a = fmaxf(a, fabsf(v2.x)); a = fmaxf(a, fabsf(v2.y)); a = fmaxf(a, fabsf(v2.z)); a = fmaxf(a, fabsf(v2.w));
    a = fmaxf(a, fabsf(v3.x)); a = fmaxf(a, fabsf(v3.y)); a = fmaxf(a, fabsf(v3.z)); a = fmaxf(a, fabsf(v3.w));

    // wave (64) butterfly max, then cross-wave via LDS
    #pragma unroll
    for (int off = 32; off >= 1; off >>= 1)
        a = fmaxf(a, __shfl_xor(a, off));
    __shared__ float red[4];
    if ((t & 63) == 0) red[t >> 6] = a;
    __syncthreads();
    float amax = fmaxf(fmaxf(red[0], red[1]), fmaxf(red[2], red[3]));

    float inv = (amax > 0.f) ? (127.0f / amax) : 0.f;
    if (t == 0) scales[row] = (amax * (1.0f / 127.0f)) * (*sw);

    int b[16];
    b[ 0] = clamp127(__float2int_rn(v0.x * inv)); b[ 1] = clamp127(__float2int_rn(v0.y * inv));
    b[ 2] = clamp127(__float2int_rn(v0.z * inv)); b[ 3] = clamp127(__float2int_rn(v0.w * inv));
    b[ 4] = clamp127(__float2int_rn(v1.x * inv)); b[ 5] = clamp127(__float2int_rn(v1.y * inv));
    b[ 6] = clamp127(__float2int_rn(v1.z * inv)); b[ 7] = clamp127(__float2int_rn(v1.w * inv));
    b[ 8] = clamp127(__float2int_rn(v2.x * inv)); b[ 9] = clamp127(__float2int_rn(v2.y * inv));
    b[10] = clamp127(__float2int_rn(v2.z * inv)); b[11] = clamp127(__float2int_rn(v2.w * inv));
    b[12] = clamp127(__float2int_rn(v3.x * inv)); b[13] = clamp127(__float2int_rn(v3.y * inv));
    b[14] = clamp127(__float2int_rn(v3.z * inv)); b[15] = clamp127(__float2int_rn(v3.w * inv));

    i32x4 w;
    w[0] = (b[0]&255) | ((b[1]&255)<<8) | ((b[2]&255)<<16) | ((b[3]&255)<<24);
    w[1] = (b[4]&255) | ((b[5]&255)<<8) | ((b[6]&255)<<16) | ((b[7]&255)<<24);
    w[2] = (b[8]&255) | ((b[9]&255)<<8) | ((b[10]&255)<<16) | ((b[11]&255)<<24);
    w[3] = (b[12]&255)| ((b[13]&255)<<8)| ((b[14]&255)<<16)| ((b[15]&255)<<24);
    *(i32x4*)(Aq + (size_t)row * KDIM + t * 16) = w;
}

// ---- qw int32 -> int8 (exact; values already in [-128,127]) ----
__global__ __launch_bounds__(256) void cvt_w(const int* __restrict__ qw, int8_t* __restrict__ Bq) {
    long i = (long)(blockIdx.x * blockDim.x + threadIdx.x) * 16;   // elem index
    const int4* p = (const int4*)(qw + i);
    int4 a = p[0], b = p[1], c = p[2], d = p[3];
    i32x4 w;
    w[0] = (a.x&255) | ((a.y&255)<<8) | ((a.z&255)<<16) | ((a.w&255)<<24);
    w[1] = (b.x&255) | ((b.y&255)<<8) | ((b.z&255)<<16) | ((b.w&255)<<24);
    w[2] = (c.x&255) | ((c.y&255)<<8) | ((c.z&255)<<16) | ((c.w&255)<<24);
    w[3] = (d.x&255) | ((d.y&255)<<8) | ((d.z&255)<<16) | ((d.w&255)<<24);
    *(i32x4*)(Bq + i) = w;
}

// ---- i8 GEMM, C[M,N] = A[M,K]*B[N,K]^T (i32 acc), epilogue y = acc*scales[m] + bias[n] ----
// LDS tiles [128 rows][64 B], XOR-swizzled 16B chunks: phys = logical ^ ((row>>1)&3)
// (same swizzle as the verified bf16 kernel: row stride is 64 B in both).
// Staging stays lane-contiguous for global_load_lds; swizzle applied by permuting
// each lane's global source chunk within the row's 64 B span.
__global__ __launch_bounds__(256) void gemm_bt_i8(
        const int8_t* __restrict__ A,    // [M,K] int8
        const int8_t* __restrict__ Bm,   // [N,K] int8
        const float* __restrict__ scales,// [M] = s_m * sw
        const float* __restrict__ bias,  // [N]
        float* __restrict__ C)           // [M,N] fp32
{
    __shared__ __align__(16) int8_t sA[BM * BK];  // 8 KB
    __shared__ __align__(16) int8_t sB[BN * BK];  // 8 KB

    const int tid  = threadIdx.x;
    const int wave = tid >> 6;
    const int lane = tid & 63;
    const int wr   = wave >> 1;       // wave row half
    const int wc   = wave & 1;        // wave col half
    const int l32  = lane & 31;
    const int hi   = lane >> 5;       // 0/1 -> k-half within fragment

    const int m0 = blockIdx.y * BM;
    const int n0 = blockIdx.x * BN;

    // ---- staging ----
    // Physical: wave stages bytes [wave*1024, +1024) (j=0) and +4096 (j=1); lane offset lane*16.
    // phys row rS = wave*16 + (lane>>2), phys chunk = lane&3; logical chunk = phys ^ ((rS>>1)&3).
    const int rS = wave * 16 + (lane >> 2);
    const int cS = ((lane & 3) ^ ((rS >> 1) & 3)) * 16;   // byte offset in row
    const int8_t* gA0 = A  + (size_t)(m0 + rS) * KDIM + cS;
    const int8_t* gA1 = gA0 + (size_t)64 * KDIM;          // rows +64: swizzle term unchanged
    const int8_t* gB0 = Bm + (size_t)(n0 + rS) * KDIM + cS;
    const int8_t* gB1 = gB0 + (size_t)64 * KDIM;
    int8_t* lA0 = sA + wave * 1024;
    int8_t* lA1 = lA0 + 4096;
    int8_t* lB0 = sB + wave * 1024;
    int8_t* lB1 = lB0 + 4096;

    // ---- fragment read addresses ----
    // A-op mfma_i32_32x32x32_i8: lane holds A[m = l32][k = hi*16 + j], j in [0,16) contiguous
    // (contiguous-doubling pattern, same family as verified bf16 16x16x32 / 32x32x16).
    // Row R = wr*64 + mi*32 + l32 -> swizzle term ((R>>1)&3) == ((l32>>1)&3).
    const int swz = (l32 >> 1) & 3;
    const int co0 = ((hi    ) ^ swz) * 16;   // ks=0: logical chunk hi
    const int co1 = ((hi + 2) ^ swz) * 16;   // ks=1: logical chunk hi+2 (k += 32)
    const int8_t* pA = sA + (wr * 64 + l32) * BK;
    const int8_t* pB = sB + (wc * 64 + l32) * BK;

    i32x16 acc[2][2];
#pragma unroll
    for (int i = 0; i < 2; i++)
#pragma unroll
        for (int j = 0; j < 2; j++)
#pragma unroll
            for (int r = 0; r < 16; r++) acc[i][j][r] = 0;

    for (int kt = 0; kt < KDIM; kt += BK) {
        __builtin_amdgcn_global_load_lds((AS1 const void*)(gA0 + kt), (AS3 void*)lA0, 16, 0, 0);
        __builtin_amdgcn_global_load_lds((AS1 const void*)(gA1 + kt), (AS3 void*)lA1, 16, 0, 0);
        __builtin_amdgcn_global_load_lds((AS1 const void*)(gB0 + kt), (AS3 void*)lB0, 16, 0, 0);
        __builtin_amdgcn_global_load_lds((AS1 const void*)(gB1 + kt), (AS3 void*)lB1, 16, 0, 0);
        __syncthreads();

        i32x4 a[2][2], b[2][2];
#pragma unroll
        for (int mi = 0; mi < 2; mi++) {
            a[mi][0] = *(const i32x4*)(pA + mi * 2048 + co0);
            a[mi][1] = *(const i32x4*)(pA + mi * 2048 + co1);
        }
#pragma unroll
        for (int ni = 0; ni < 2; ni++) {
            b[ni][0] = *(const i32x4*)(pB + ni * 2048 + co0);
            b[ni][1] = *(const i32x4*)(pB + ni * 2048 + co1);
        }

#pragma unroll
        for (int ks = 0; ks < 2; ks++)
#pragma unroll
            for (int mi = 0; mi < 2; mi++)
#pragma unroll
                for (int ni = 0; ni < 2; ni++)
                    acc[mi][ni] = __builtin_amdgcn_mfma_i32_32x32x32_i8(
                        a[mi][ks], b[ni][ks], acc[mi][ni], 0, 0, 0);

        __syncthreads();
    }

    // ---- epilogue ----
    // C/D 32x32 layout: col = l32, row = (r&3) + 8*(r>>2) + 4*hi, r in [0,16)  [m74/m101]
#pragma unroll
    for (int mi = 0; mi < 2; mi++) {
        const int row_base = m0 + wr * 64 + mi * 32 + 4 * hi;
        float sc[16];
#pragma unroll
        for (int r = 0; r < 16; r++)
            sc[r] = scales[row_base + (r & 3) + 8 * (r >> 2)];
#pragma unroll
        for (int ni = 0; ni < 2; ni++) {
            const int col = n0 + wc * 64 + ni * 32 + l32;
            const float bc = bias[col];
#pragma unroll
            for (int r = 0; r < 16; r++) {
                const int row = row_base + (r & 3) + 8 * (r >> 2);
                C[(size_t)row * NDIM + col] = (float)acc[mi][ni][r] * sc[r] + bc;
            }
        }
    }
}

// ---- correctness fallback if workspace is too small (not expected to run) ----
__global__ void gemm_naive_f32(const float* __restrict__ x, const int* __restrict__ qw,
                               const float* __restrict__ sw, const float* __restrict__ bias,
                               float* __restrict__ out) {
    size_t id = (size_t)blockIdx.x * blockDim.x + threadIdx.x;
    if (id >= (size_t)MDIM * NDIM) return;
    int m = (int)(id / NDIM);
    int n = (int)(id % NDIM);
    const float* xr = x + (size_t)m * KDIM;
    const int*   wr = qw + (size_t)n * KDIM;
    float acc = 0.f;
    for (int k = 0; k < KDIM; k++) acc += xr[k] * (float)wr[k];
    out[id] = acc * (*sw) + bias[n];
}

extern "C" void kernel_launch(void* const* d_in, const int* in_sizes, int n_in,
                              void* d_out, int out_size, void* d_ws, size_t ws_size,
                              hipStream_t stream) {
    const float* x    = (const float*)d_in[0];
    const int*   qw   = (const int*)d_in[1];
    const float* sw   = (const float*)d_in[2];
    const float* bias = (const float*)d_in[3];
    float* out = (float*)d_out;

    const size_t needA = (size_t)MDIM * KDIM;                  // 32 MiB int8
    const size_t needB = (size_t)NDIM * KDIM;                  // 16 MiB int8
    const size_t needS = (size_t)MDIM * sizeof(float);         // 32 KiB scales

    if (ws_size >= needA + needB + needS) {
        int8_t* Aq = (int8_t*)d_ws;
        int8_t* Bq = Aq + needA;
        float*  scales = (float*)(Bq + needB);

        quant_x<<<MDIM, 256, 0, stream>>>(x, sw, Aq, scales);
        const long nw = (long)NDIM * KDIM;                     // 16,777,216
        cvt_w<<<(int)(nw / (256 * 16)), 256, 0, stream>>>(qw, Bq);

        dim3 grid(NDIM / BN, MDIM / BM);                       // (32, 64) = 2048 blocks
        gemm_bt_i8<<<grid, 256, 0, stream>>>(Aq, Bq, scales, bias, out);
    } else {
        size_t total = (size_t)MDIM * NDIM;
        gemm_naive_f32<<<(total + 255) / 256, 256, 0, stream>>>(x, qw, sw, bias, out);
    }
}

// Round 4
// 422.122 us; speedup vs baseline: 1.3395x; 1.0285x over previous
//
#include <hip/hip_runtime.h>
#include <stdint.h>

// Problem constants (B=4, S=2048, K=4096, N=4096 -> M = B*S = 8192)
#define MDIM 8192
#define NDIM 4096
#define KDIM 4096

// GEMM tiling: 128x128 tile, BK=64 (i8 -> 64B rows), 4 waves (2x2),
// each wave 64x64 via 2x2 grid of mfma_i32_32x32x32_i8. Double-buffered LDS.
#define BM 128
#define BN 128
#define BK 64

typedef __attribute__((ext_vector_type(4)))  int i32x4;
typedef __attribute__((ext_vector_type(16))) int i32x16;

#define AS1 __attribute__((address_space(1)))
#define AS3 __attribute__((address_space(3)))

__device__ __forceinline__ int clamp127(int v) {
    return v > 127 ? 127 : (v < -127 ? -127 : v);
}

// ---- x fp32 -> int8, per-row symmetric quant (row = 4096 elems) ----
// One block per row. scales[row] = (amax/127) * sw  (dequant scale, sw folded in).
// Loads: lane-contiguous float4 (16B/lane). Stores: packed 4B/lane. Both coalesced.
__global__ __launch_bounds__(256) void quant_x(
        const float* __restrict__ x, const float* __restrict__ sw,
        int8_t* __restrict__ Aq, float* __restrict__ scales) {
    const int row = blockIdx.x;
    const int t   = threadIdx.x;
    const float4* px = (const float4*)(x + (size_t)row * KDIM);

    float4 v[4];
#pragma unroll
    for (int j = 0; j < 4; j++) v[j] = px[t + 256 * j];

    float a = 0.f;
#pragma unroll
    for (int j = 0; j < 4; j++) {
        a = fmaxf(a, fabsf(v[j].x)); a = fmaxf(a, fabsf(v[j].y));
        a = fmaxf(a, fabsf(v[j].z)); a = fmaxf(a, fabsf(v[j].w));
    }
#pragma unroll
    for (int off = 32; off >= 1; off >>= 1)
        a = fmaxf(a, __shfl_xor(a, off));
    __shared__ float red[4];
    if ((t & 63) == 0) red[t >> 6] = a;
    __syncthreads();
    const float amax = fmaxf(fmaxf(red[0], red[1]), fmaxf(red[2], red[3]));
    const float inv  = (amax > 0.f) ? (127.0f / amax) : 0.f;
    if (t == 0) scales[row] = (amax * (1.0f / 127.0f)) * (*sw);

    int* out32 = (int*)(Aq + (size_t)row * KDIM);
#pragma unroll
    for (int j = 0; j < 4; j++) {
        int b0 = clamp127(__float2int_rn(v[j].x * inv));
        int b1 = clamp127(__float2int_rn(v[j].y * inv));
        int b2 = clamp127(__float2int_rn(v[j].z * inv));
        int b3 = clamp127(__float2int_rn(v[j].w * inv));
        out32[t + 256 * j] = (b0 & 255) | ((b1 & 255) << 8) | ((b2 & 255) << 16) | ((b3 & 255) << 24);
    }
}

// ---- qw int32 -> int8 (exact; values already in [-128,127]) ----
// Lane-contiguous int4 load (16B/lane), packed 4B/lane store.
__global__ __launch_bounds__(256) void cvt_w(const int* __restrict__ qw, int8_t* __restrict__ Bq) {
    const long i = (long)blockIdx.x * 256 + threadIdx.x;   // one int4 (4 elems) per thread
    int4 a = ((const int4*)qw)[i];
    ((int*)Bq)[i] = (a.x & 255) | ((a.y & 255) << 8) | ((a.z & 255) << 16) | ((a.w & 255) << 24);
}

// ---- i8 GEMM, C[M,N] = A[M,K]*B[N,K]^T (i32 acc), epilogue y = acc*scales[m] + bias[n] ----
// LDS tiles [128 rows][64 B], XOR-swizzled 16B chunks: phys = logical ^ ((row>>1)&3).
// Double-buffered: prefetch tile k+1 issued right after the barrier that publishes
// tile k, so its vmcnt(0) drain (compiler-emitted before the NEXT s_barrier) lands
// a full compute-phase later -- the global-load latency is hidden instead of being
// eaten at every barrier (R3: 960 cyc/block-iter vs 320-cyc LDS floor).
__global__ __launch_bounds__(256, 3) void gemm_bt_i8(
        const int8_t* __restrict__ A,    // [M,K] int8
        const int8_t* __restrict__ Bm,   // [N,K] int8
        const float* __restrict__ scales,// [M] = s_m * sw
        const float* __restrict__ bias,  // [N]
        float* __restrict__ C)           // [M,N] fp32
{
    __shared__ __align__(16) int8_t sA[2][BM * BK];  // 2 x 8 KB
    __shared__ __align__(16) int8_t sB[2][BN * BK];  // 2 x 8 KB

    const int tid  = threadIdx.x;
    const int wave = tid >> 6;
    const int lane = tid & 63;
    const int wr   = wave >> 1;       // wave row half
    const int wc   = wave & 1;        // wave col half
    const int l32  = lane & 31;
    const int hi   = lane >> 5;       // 0/1 -> k-half within fragment

    const int m0 = blockIdx.y * BM;
    const int n0 = blockIdx.x * BN;

    // ---- staging (lane-contiguous LDS dest: base + lane*16, per global_load_lds HW) ----
    // phys row rS = wave*16 + (lane>>2), phys chunk = lane&3; source chunk = phys ^ ((rS>>1)&3).
    const int rS = wave * 16 + (lane >> 2);
    const int cS = ((lane & 3) ^ ((rS >> 1) & 3)) * 16;   // swizzled source byte offset in row
    const int8_t* gA0 = A  + (size_t)(m0 + rS) * KDIM + cS;
    const int8_t* gA1 = gA0 + (size_t)64 * KDIM;          // rows +64: swizzle term unchanged
    const int8_t* gB0 = Bm + (size_t)(n0 + rS) * KDIM + cS;
    const int8_t* gB1 = gB0 + (size_t)64 * KDIM;
    const int stoff = wave * 1024;                        // wave-uniform LDS byte base

    // ---- fragment read addresses ----
    // A-op: lane holds A[m = l32][k = hi*16 + j], j in [0,16). Row R = wr*64+mi*32+l32
    // -> swizzle term ((R>>1)&3) == ((l32>>1)&3).
    const int swz = (l32 >> 1) & 3;
    const int co0 = ((hi    ) ^ swz) * 16;   // ks=0 chunk
    const int co1 = ((hi + 2) ^ swz) * 16;   // ks=1 chunk (k += 32)
    const int rdA = (wr * 64 + l32) * BK;
    const int rdB = (wc * 64 + l32) * BK;

    i32x16 acc[2][2];
#pragma unroll
    for (int i = 0; i < 2; i++)
#pragma unroll
        for (int j = 0; j < 2; j++)
#pragma unroll
            for (int r = 0; r < 16; r++) acc[i][j][r] = 0;

    auto prefetch = [&](int buf, int kt) {
        __builtin_amdgcn_global_load_lds((AS1 const void*)(gA0 + kt), (AS3 void*)(&sA[buf][stoff]),        16, 0, 0);
        __builtin_amdgcn_global_load_lds((AS1 const void*)(gA1 + kt), (AS3 void*)(&sA[buf][stoff + 4096]), 16, 0, 0);
        __builtin_amdgcn_global_load_lds((AS1 const void*)(gB0 + kt), (AS3 void*)(&sB[buf][stoff]),        16, 0, 0);
        __builtin_amdgcn_global_load_lds((AS1 const void*)(gB1 + kt), (AS3 void*)(&sB[buf][stoff + 4096]), 16, 0, 0);
    };
    auto compute = [&](int buf) {
        const int8_t* pA = &sA[buf][rdA];
        const int8_t* pB = &sB[buf][rdB];
        i32x4 a[2][2], b[2][2];
#pragma unroll
        for (int mi = 0; mi < 2; mi++) {
            a[mi][0] = *(const i32x4*)(pA + mi * 2048 + co0);
            a[mi][1] = *(const i32x4*)(pA + mi * 2048 + co1);
        }
#pragma unroll
        for (int ni = 0; ni < 2; ni++) {
            b[ni][0] = *(const i32x4*)(pB + ni * 2048 + co0);
            b[ni][1] = *(const i32x4*)(pB + ni * 2048 + co1);
        }
#pragma unroll
        for (int ks = 0; ks < 2; ks++)
#pragma unroll
            for (int mi = 0; mi < 2; mi++)
#pragma unroll
                for (int ni = 0; ni < 2; ni++)
                    acc[mi][ni] = __builtin_amdgcn_mfma_i32_32x32x32_i8(
                        a[mi][ks], b[ni][ks], acc[mi][ni], 0, 0, 0);
    };

    // ---- pipelined K-loop: tiles 0..63, one barrier per tile ----
    prefetch(0, 0);
    for (int kt = 0; kt < KDIM - 2 * BK; kt += 2 * BK) {   // 31 iterations
        __syncthreads();            // publishes buf0 (tile kt); drains its vmem
        prefetch(1, kt + BK);       // in flight across compute(0)
        compute(0);
        __syncthreads();            // publishes buf1; all waves done reading buf0
        prefetch(0, kt + 2 * BK);   // in flight across compute(1)
        compute(1);
    }
    __syncthreads();
    prefetch(1, KDIM - BK);         // tile 63
    compute(0);                     // tile 62
    __syncthreads();
    compute(1);                     // tile 63

    // ---- epilogue ----
    // C/D 32x32 layout: col = l32, row = (r&3) + 8*(r>>2) + 4*hi, r in [0,16)  [m74/m101]
#pragma unroll
    for (int mi = 0; mi < 2; mi++) {
        const int row_base = m0 + wr * 64 + mi * 32 + 4 * hi;
        float sc[16];
#pragma unroll
        for (int r = 0; r < 16; r++)
            sc[r] = scales[row_base + (r & 3) + 8 * (r >> 2)];
#pragma unroll
        for (int ni = 0; ni < 2; ni++) {
            const int col = n0 + wc * 64 + ni * 32 + l32;
            const float bc = bias[col];
#pragma unroll
            for (int r = 0; r < 16; r++) {
                const int row = row_base + (r & 3) + 8 * (r >> 2);
                C[(size_t)row * NDIM + col] = (float)acc[mi][ni][r] * sc[r] + bc;
            }
        }
    }
}

// ---- correctness fallback if workspace is too small (not expected to run) ----
__global__ void gemm_naive_f32(const float* __restrict__ x, const int* __restrict__ qw,
                               const float* __restrict__ sw, const float* __restrict__ bias,
                               float* __restrict__ out) {
    size_t id = (size_t)blockIdx.x * blockDim.x + threadIdx.x;
    if (id >= (size_t)MDIM * NDIM) return;
    int m = (int)(id / NDIM);
    int n = (int)(id % NDIM);
    const float* xr = x + (size_t)m * KDIM;
    const int*   wr = qw + (size_t)n * KDIM;
    float acc = 0.f;
    for (int k = 0; k < KDIM; k++) acc += xr[k] * (float)wr[k];
    out[id] = acc * (*sw) + bias[n];
}

extern "C" void kernel_launch(void* const* d_in, const int* in_sizes, int n_in,
                              void* d_out, int out_size, void* d_ws, size_t ws_size,
                              hipStream_t stream) {
    const float* x    = (const float*)d_in[0];
    const int*   qw   = (const int*)d_in[1];
    const float* sw   = (const float*)d_in[2];
    const float* bias = (const float*)d_in[3];
    float* out = (float*)d_out;

    const size_t needA = (size_t)MDIM * KDIM;                  // 32 MiB int8
    const size_t needB = (size_t)NDIM * KDIM;                  // 16 MiB int8
    const size_t needS = (size_t)MDIM * sizeof(float);         // 32 KiB scales

    if (ws_size >= needA + needB + needS) {
        int8_t* Aq = (int8_t*)d_ws;
        int8_t* Bq = Aq + needA;
        float*  scales = (float*)(Bq + needB);

        quant_x<<<MDIM, 256, 0, stream>>>(x, sw, Aq, scales);
        const long nw4 = (long)NDIM * KDIM / 4;                // int4-granular threads
        cvt_w<<<(int)(nw4 / 256), 256, 0, stream>>>(qw, Bq);

        dim3 grid(NDIM / BN, MDIM / BM);                       // (32, 64) = 2048 blocks
        gemm_bt_i8<<<grid, 256, 0, stream>>>(Aq, Bq, scales, bias, out);
    } else {
        size_t total = (size_t)MDIM * NDIM;
        gemm_naive_f32<<<(total + 255) / 256, 256, 0, stream>>>(x, qw, sw, bias, out);
    }
}